// Round 6
// baseline (809.073 us; speedup 1.0000x reference)
//
#include <hip/hip_runtime.h>
#include <math.h>

#define TSTEPS 6
#define NN 20000
#define NE 320000
#define INF 11
#define XPAD 16   // padded feature stride for x-side buffers
#define HID 64
#define OUTF 3
#define NPW 4     // nodes per wave in fused kernels (NN % (8*NPW) == 0)

__device__ __forceinline__ float bcast(float v, int l) {
    return __uint_as_float(__builtin_amdgcn_readlane(__float_as_uint(v), l));
}

// overflow-safe fast tanh: e2 in (0,1], no inf/NaN for any finite a
__device__ __forceinline__ float tanh_safe(float a) {
    float e2 = __expf(-2.0f * fabsf(a));
    float t = (1.0f - e2) / (1.0f + e2);
    return copysignf(t, a);
}

// ---------------- graph-structure kernels (once per call) ----------------

__global__ void k_deg(const int* __restrict__ src, float* __restrict__ deg, int E) {
    int e = blockIdx.x * blockDim.x + threadIdx.x;
    if (e < E) atomicAdd(&deg[src[e]], 1.0f);
}

__global__ void k_dis(float* deg, int n) {
    int i = blockIdx.x * blockDim.x + threadIdx.x;
    if (i < n) {
        float d = deg[i];
        deg[i] = d > 0.0f ? rsqrtf(fmaxf(d, 1.0f)) : 0.0f;
    }
}

__global__ void k_ew(const int* __restrict__ src, const int* __restrict__ dst,
                     const float* __restrict__ dis, float* __restrict__ ew, int E) {
    int e = blockIdx.x * blockDim.x + threadIdx.x;
    if (e < E) ew[e] = -dis[src[e]] * dis[dst[e]];
}

__global__ void k_indeg(const int* __restrict__ dst, int* __restrict__ indeg, int E) {
    int e = blockIdx.x * blockDim.x + threadIdx.x;
    if (e < E) atomicAdd(&indeg[dst[e]], 1);
}

// exclusive scan of indeg[0..n) -> rowstart[0..n], single block of 1024
__global__ __launch_bounds__(1024) void k_scan(const int* __restrict__ in,
                                               int* __restrict__ out, int n) {
    __shared__ int buf[1024];
    __shared__ int carry;
    if (threadIdx.x == 0) carry = 0;
    __syncthreads();
    for (int base = 0; base < n; base += 1024) {
        int i = base + (int)threadIdx.x;
        int v = (i < n) ? in[i] : 0;
        buf[threadIdx.x] = v;
        __syncthreads();
        for (int off = 1; off < 1024; off <<= 1) {
            int t = (threadIdx.x >= (unsigned)off) ? buf[threadIdx.x - off] : 0;
            __syncthreads();
            buf[threadIdx.x] += t;
            __syncthreads();
        }
        if (i < n) out[i] = carry + buf[threadIdx.x] - v;  // exclusive
        __syncthreads();
        if (threadIdx.x == 0) carry += buf[1023];
        __syncthreads();
    }
    if (threadIdx.x == 0) out[n] = carry;
}

// fill CSR: permuted src + ew, bucketed by dst
__global__ void k_fill(const int* __restrict__ src, const int* __restrict__ dst,
                       const float* __restrict__ ew, int* __restrict__ cursor,
                       int* __restrict__ perm_src, float* __restrict__ perm_ew, int E) {
    int e = blockIdx.x * blockDim.x + threadIdx.x;
    if (e >= E) return;
    int pos = atomicAdd(&cursor[dst[e]], 1);
    perm_src[pos] = src[e];
    perm_ew[pos] = ew[e];
}

// ---------------- weight packing (once per call) ----------------
__global__ void k_packh4(const float* __restrict__ Wh, float4* __restrict__ out) {
    int idx = blockIdx.x * blockDim.x + threadIdx.x;
    if (idx >= HID * HID) return;
    int j = idx >> 6, f = idx & 63;
    float4 v;
    v.x = Wh[((0 * 2 + 0) * HID + j) * HID + f];
    v.y = Wh[((0 * 2 + 1) * HID + j) * HID + f];
    v.z = Wh[((1 * 2 + 0) * HID + j) * HID + f];
    v.w = Wh[((1 * 2 + 1) * HID + j) * HID + f];
    out[idx] = v;
}
__global__ void k_packh2(const float* __restrict__ Wh, float2* __restrict__ out) {
    int idx = blockIdx.x * blockDim.x + threadIdx.x;
    if (idx >= HID * HID) return;
    int j = idx >> 6, f = idx & 63;
    float2 v;
    v.x = Wh[((2 * 2 + 0) * HID + j) * HID + f];
    v.y = Wh[((2 * 2 + 1) * HID + j) * HID + f];
    out[idx] = v;
}
__global__ void k_packx4(const float* __restrict__ Wx, float4* __restrict__ out) {
    int idx = blockIdx.x * blockDim.x + threadIdx.x;
    if (idx >= INF * HID) return;
    int i = idx >> 6, f = idx & 63;
    float4 v;
    v.x = Wx[((0 * 2 + 0) * INF + i) * HID + f];
    v.y = Wx[((0 * 2 + 1) * INF + i) * HID + f];
    v.z = Wx[((1 * 2 + 0) * INF + i) * HID + f];
    v.w = Wx[((1 * 2 + 1) * INF + i) * HID + f];
    out[idx] = v;
}
__global__ void k_packx2(const float* __restrict__ Wx, float2* __restrict__ out) {
    int idx = blockIdx.x * blockDim.x + threadIdx.x;
    if (idx >= INF * HID) return;
    int i = idx >> 6, f = idx & 63;
    float2 v;
    v.x = Wx[((2 * 2 + 0) * INF + i) * HID + f];
    v.y = Wx[((2 * 2 + 1) * INF + i) * HID + f];
    out[idx] = v;
}

// ---------------- per-timestep kernels ----------------

// t == 0: x_in = X_seq[0], padded to stride 16
__global__ void k_xin0(const float* __restrict__ Xt, float* __restrict__ xin, int n) {
    int i = blockIdx.x * blockDim.x + threadIdx.x;
    if (i >= n) return;
    const float* xt = Xt + (size_t)i * INF;
    float* xo = xin + (size_t)i * XPAD;
#pragma unroll
    for (int k = 0; k < INF; ++k) xo[k] = xt[k];
#pragma unroll
    for (int k = INF; k < XPAD; ++k) xo[k] = 0.0f;
}

// t > 0: cols 3:6 <- u_prev, cols 8:11 <- (u_prev - X_prev[:,3:6]) / dt
__global__ void k_xin(const float* __restrict__ Xt, const float* __restrict__ Xp,
                      const float* __restrict__ uprev, float* __restrict__ xin, int n) {
    int i = blockIdx.x * blockDim.x + threadIdx.x;
    if (i >= n) return;
    const float* xt = Xt + (size_t)i * INF;
    const float* xp = Xp + (size_t)i * INF;
    const float* up = uprev + (size_t)i * OUTF;
    float* xo = xin + (size_t)i * XPAD;
    float dt = xt[6] - xp[6];
    float inv = 1.0f / dt;
    xo[0] = xt[0]; xo[1] = xt[1]; xo[2] = xt[2];
    xo[3] = up[0]; xo[4] = up[1]; xo[5] = up[2];
    xo[6] = xt[6]; xo[7] = xt[7];
    xo[8] = (up[0] - xp[3]) * inv;
    xo[9] = (up[1] - xp[4]) * inv;
    xo[10] = (up[2] - xp[5]) * inv;
    xo[11] = 0.0f; xo[12] = 0.0f; xo[13] = 0.0f; xo[14] = 0.0f; xo[15] = 0.0f;
}

// Fused: gather Lhat*x (16-wide) + Lhat*h (64-wide) into registers, then Z/R gates.
// 512 threads = 8 waves, NPW nodes/wave -> 32 nodes/block. Wh4 staged in LDS (64KB).
__global__ __launch_bounds__(512) void k_aggates(
    const int* __restrict__ rowstart, const int* __restrict__ perm_src,
    const float* __restrict__ perm_ew,
    const float* __restrict__ xin, float* __restrict__ t1x,
    const float* __restrict__ h,
    const float4* __restrict__ Wx4, const float* __restrict__ bx,
    const float4* __restrict__ Wh4, const float* __restrict__ bh,
    float* __restrict__ Zb, float* __restrict__ hr, int n) {
    __shared__ float4 sWh[HID * HID];  // 64 KB
    for (int i = threadIdx.x; i < HID * HID; i += 512) sWh[i] = Wh4[i];

    int wid = (int)((blockIdx.x * blockDim.x + threadIdx.x) >> 6);
    int wbase = wid * NPW;
    int lane = threadIdx.x & 63;
    int f16 = lane & 15, eo = lane >> 4;
    bool act = (wbase < n);

    float t1xv[NPW], thg[NPW], hv[NPW];
    if (act) {
#pragma unroll
        for (int nn = 0; nn < NPW; ++nn) {
            int node = wbase + nn;
            int s = rowstart[node], e = rowstart[node + 1];
            // 16-wide x gather (4 edges/iter across lane groups)
            float a = 0.0f;
            for (int p = s + eo; p < e; p += 4)
                a = fmaf(perm_ew[p], xin[(size_t)perm_src[p] * XPAD + f16], a);
            a += __shfl_down(a, 32);
            a += __shfl_down(a, 16);
            t1xv[nn] = a;  // valid in lanes 0..15
            // 64-wide h gather, 4 in flight
            float a0 = 0.0f, a1 = 0.0f, a2 = 0.0f, a3 = 0.0f;
            int p = s;
            for (; p + 3 < e; p += 4) {
                int s0 = perm_src[p], s1 = perm_src[p + 1];
                int s2 = perm_src[p + 2], s3 = perm_src[p + 3];
                float w0 = perm_ew[p], w1 = perm_ew[p + 1];
                float w2 = perm_ew[p + 2], w3 = perm_ew[p + 3];
                a0 = fmaf(w0, h[(size_t)s0 * HID + lane], a0);
                a1 = fmaf(w1, h[(size_t)s1 * HID + lane], a1);
                a2 = fmaf(w2, h[(size_t)s2 * HID + lane], a2);
                a3 = fmaf(w3, h[(size_t)s3 * HID + lane], a3);
            }
            for (; p < e; ++p)
                a0 = fmaf(perm_ew[p], h[(size_t)perm_src[p] * HID + lane], a0);
            thg[nn] = (a0 + a1) + (a2 + a3);
            hv[nn] = h[(size_t)node * HID + lane];
        }
        // persist t1x for k_aggcand
#pragma unroll
        for (int nn = 0; nn < NPW; ++nn)
            if (lane < 16) t1x[(size_t)(wbase + nn) * XPAD + lane] = t1xv[nn];
    }
    __syncthreads();
    if (!act) return;

    float xrow = xin[(size_t)wbase * XPAD + lane];  // 4 nodes x 16 padded feats
    float b0z = bx[0 * HID + lane] + bh[0 * HID + lane];
    float b0r = bx[1 * HID + lane] + bh[1 * HID + lane];
    float az[NPW], ar[NPW];
#pragma unroll
    for (int nn = 0; nn < NPW; ++nn) { az[nn] = b0z; ar[nn] = b0r; }
    // x-side (Wx4 is 11KB -> L1-resident, keep global)
#pragma unroll
    for (int i = 0; i < INF; ++i) {
        float4 w = Wx4[i * HID + lane];
#pragma unroll
        for (int nn = 0; nn < NPW; ++nn) {
            float xv = bcast(xrow, nn * XPAD + i);
            float tv = bcast(t1xv[nn], i);
            az[nn] = fmaf(xv, w.x, fmaf(tv, w.y, az[nn]));
            ar[nn] = fmaf(xv, w.z, fmaf(tv, w.w, ar[nn]));
        }
    }
    // h-side from LDS
#pragma unroll 8
    for (int j = 0; j < HID; ++j) {
        float4 w = sWh[j * HID + lane];
#pragma unroll
        for (int nn = 0; nn < NPW; ++nn) {
            float hj = bcast(hv[nn], j);
            float tj = bcast(thg[nn], j);
            az[nn] = fmaf(hj, w.x, fmaf(tj, w.y, az[nn]));
            ar[nn] = fmaf(hj, w.z, fmaf(tj, w.w, ar[nn]));
        }
    }
#pragma unroll
    for (int nn = 0; nn < NPW; ++nn) {
        int node = wbase + nn;
        float Z = 1.0f / (1.0f + __expf(-az[nn]));
        float R = 1.0f / (1.0f + __expf(-ar[nn]));
        Zb[(size_t)node * HID + lane] = Z;
        hr[(size_t)node * HID + lane] = hv[nn] * R;
    }
}

// Fused: gather Lhat*(h*R) + candidate + blend + head. Wh2/Wx2/head in LDS (~38KB).
__global__ __launch_bounds__(512) void k_aggcand(
    const int* __restrict__ rowstart, const int* __restrict__ perm_src,
    const float* __restrict__ perm_ew,
    const float* __restrict__ xin, const float* __restrict__ t1x,
    float* __restrict__ h, const float* __restrict__ hr,
    const float2* __restrict__ Wx2, const float* __restrict__ bx,
    const float2* __restrict__ Wh2, const float* __restrict__ bh,
    const float* __restrict__ Zb,
    const float* __restrict__ hw, const float* __restrict__ hb,
    float* __restrict__ out, int n) {
    __shared__ float2 sWh[HID * HID];    // 32 KB
    __shared__ float2 sWx[INF * HID];    // 5.5 KB
    __shared__ float shw[HID * OUTF];    // 768 B
    for (int i = threadIdx.x; i < HID * HID; i += 512) sWh[i] = Wh2[i];
    for (int i = threadIdx.x; i < INF * HID; i += 512) sWx[i] = Wx2[i];
    for (int i = threadIdx.x; i < HID * OUTF; i += 512) shw[i] = hw[i];

    int wid = (int)((blockIdx.x * blockDim.x + threadIdx.x) >> 6);
    int wbase = wid * NPW;
    int lane = threadIdx.x & 63;
    bool act = (wbase < n);

    float thg[NPW];
    if (act) {
#pragma unroll
        for (int nn = 0; nn < NPW; ++nn) {
            int node = wbase + nn;
            int s = rowstart[node], e = rowstart[node + 1];
            float a0 = 0.0f, a1 = 0.0f, a2 = 0.0f, a3 = 0.0f;
            int p = s;
            for (; p + 3 < e; p += 4) {
                int s0 = perm_src[p], s1 = perm_src[p + 1];
                int s2 = perm_src[p + 2], s3 = perm_src[p + 3];
                float w0 = perm_ew[p], w1 = perm_ew[p + 1];
                float w2 = perm_ew[p + 2], w3 = perm_ew[p + 3];
                a0 = fmaf(w0, hr[(size_t)s0 * HID + lane], a0);
                a1 = fmaf(w1, hr[(size_t)s1 * HID + lane], a1);
                a2 = fmaf(w2, hr[(size_t)s2 * HID + lane], a2);
                a3 = fmaf(w3, hr[(size_t)s3 * HID + lane], a3);
            }
            for (; p < e; ++p)
                a0 = fmaf(perm_ew[p], hr[(size_t)perm_src[p] * HID + lane], a0);
            thg[nn] = (a0 + a1) + (a2 + a3);
        }
    }
    __syncthreads();
    if (!act) return;

    float xrow = xin[(size_t)wbase * XPAD + lane];
    float trow = t1x[(size_t)wbase * XPAD + lane];
    float b0 = bx[2 * HID + lane] + bh[2 * HID + lane];
    float ah[NPW], hrv[NPW];
#pragma unroll
    for (int nn = 0; nn < NPW; ++nn) {
        ah[nn] = b0;
        hrv[nn] = hr[(size_t)(wbase + nn) * HID + lane];
    }
#pragma unroll
    for (int i = 0; i < INF; ++i) {
        float2 w = sWx[i * HID + lane];
#pragma unroll
        for (int nn = 0; nn < NPW; ++nn) {
            float xv = bcast(xrow, nn * XPAD + i);
            float tv = bcast(trow, nn * XPAD + i);
            ah[nn] = fmaf(xv, w.x, fmaf(tv, w.y, ah[nn]));
        }
    }
#pragma unroll 8
    for (int j = 0; j < HID; ++j) {
        float2 w = sWh[j * HID + lane];
#pragma unroll
        for (int nn = 0; nn < NPW; ++nn) {
            float hj = bcast(hrv[nn], j);
            float tj = bcast(thg[nn], j);
            ah[nn] = fmaf(hj, w.x, fmaf(tj, w.y, ah[nn]));
        }
    }
#pragma unroll
    for (int nn = 0; nn < NPW; ++nn) {
        int node = wbase + nn;
        float Ht = tanh_safe(ah[nn]);
        float z = Zb[(size_t)node * HID + lane];
        float hv = h[(size_t)node * HID + lane];
        float hnew = z * hv + (1.0f - z) * Ht;
        h[(size_t)node * HID + lane] = hnew;
#pragma unroll
        for (int o = 0; o < OUTF; ++o) {
            float v = hnew * shw[lane * OUTF + o];
            for (int off = 32; off; off >>= 1) v += __shfl_down(v, off);
            if (lane == 0) out[(size_t)node * OUTF + o] = v + hb[o];
        }
    }
}

extern "C" void kernel_launch(void* const* d_in, const int* in_sizes, int n_in,
                              void* d_out, int out_size, void* d_ws, size_t ws_size,
                              hipStream_t stream) {
    const float* X_seq = (const float*)d_in[0];    // [6, 20000, 11]
    const int* edge = (const int*)d_in[1];         // [2, 320000]
    const float* Wx = (const float*)d_in[2];       // [3, 2, 11, 64]
    const float* bx = (const float*)d_in[3];       // [3, 64]
    const float* Wh = (const float*)d_in[4];       // [3, 2, 64, 64]
    const float* bh = (const float*)d_in[5];       // [3, 64]
    const float* head_W = (const float*)d_in[6];   // [64, 3]
    const float* head_b = (const float*)d_in[7];   // [3]
    float* out = (float*)d_out;                    // [6, 20000, 3]

    const int* src = edge;
    const int* dst = edge + NE;

    // workspace layout (floats). Packed weights first for 16B alignment.
    float* ws = (float*)d_ws;
    float4* Wh4g   = (float4*)ws;                       // 4096 float4 = 16384 f
    float4* Wx4g   = (float4*)(ws + 16384);             // 704 float4  = 2816 f
    float2* Wh2c   = (float2*)(ws + 16384 + 2816);      // 4096 float2 = 8192 f
    float2* Wx2c   = (float2*)(ws + 16384 + 2816 + 8192); // 704 float2 = 1408 f
    float* fbase   = ws + 28800;
    float* dis      = fbase;                      // N
    float* ew       = dis + NN;                   // E
    float* perm_ew  = ew + NE;                    // E
    float* xin      = perm_ew + NE;               // N*16
    float* t1x      = xin + NN * XPAD;            // N*16
    float* h        = t1x + NN * XPAD;            // N*64
    float* Zb       = h + NN * HID;               // N*64
    float* hr       = Zb + NN * HID;              // N*64
    int* indeg      = (int*)(hr + NN * HID);      // N
    int* rowstart   = indeg + NN;                 // N+1
    int* cursor     = rowstart + NN + 1;          // N
    int* perm_src   = cursor + NN;                // E

    // --- graph structure + weight packing (once per call) ---
    hipMemsetAsync(dis, 0, NN * sizeof(float), stream);
    hipMemsetAsync(indeg, 0, NN * sizeof(int), stream);
    k_deg<<<(NE + 255) / 256, 256, 0, stream>>>(src, dis, NE);
    k_dis<<<(NN + 255) / 256, 256, 0, stream>>>(dis, NN);
    k_ew<<<(NE + 255) / 256, 256, 0, stream>>>(src, dst, dis, ew, NE);
    k_indeg<<<(NE + 255) / 256, 256, 0, stream>>>(dst, indeg, NE);
    k_scan<<<1, 1024, 0, stream>>>(indeg, rowstart, NN);
    hipMemcpyAsync(cursor, rowstart, NN * sizeof(int), hipMemcpyDeviceToDevice, stream);
    k_fill<<<(NE + 255) / 256, 256, 0, stream>>>(src, dst, ew, cursor, perm_src, perm_ew, NE);
    k_packh4<<<(HID * HID + 255) / 256, 256, 0, stream>>>(Wh, Wh4g);
    k_packh2<<<(HID * HID + 255) / 256, 256, 0, stream>>>(Wh, Wh2c);
    k_packx4<<<(INF * HID + 255) / 256, 256, 0, stream>>>(Wx, Wx4g);
    k_packx2<<<(INF * HID + 255) / 256, 256, 0, stream>>>(Wx, Wx2c);

    // h0 = 0
    hipMemsetAsync(h, 0, NN * HID * sizeof(float), stream);

    // fused kernels: 512 threads = 8 waves x NPW nodes = 32 nodes/block
    const int fused_grid = (NN + 8 * NPW - 1) / (8 * NPW);  // 625

    for (int t = 0; t < TSTEPS; ++t) {
        const float* Xt = X_seq + (size_t)t * NN * INF;

        if (t == 0) {
            k_xin0<<<(NN + 255) / 256, 256, 0, stream>>>(Xt, xin, NN);
        } else {
            const float* Xp = X_seq + (size_t)(t - 1) * NN * INF;
            const float* uprev = out + (size_t)(t - 1) * NN * OUTF;
            k_xin<<<(NN + 255) / 256, 256, 0, stream>>>(Xt, Xp, uprev, xin, NN);
        }

        k_aggates<<<fused_grid, 512, 0, stream>>>(rowstart, perm_src, perm_ew,
                                                  xin, t1x, h, Wx4g, bx, Wh4g, bh,
                                                  Zb, hr, NN);

        k_aggcand<<<fused_grid, 512, 0, stream>>>(rowstart, perm_src, perm_ew,
                                                  xin, t1x, h, hr, Wx2c, bx, Wh2c, bh,
                                                  Zb, head_W, head_b,
                                                  out + (size_t)t * NN * OUTF, NN);
    }
}

// Round 7
// 666.529 us; speedup vs baseline: 1.2139x; 1.2139x over previous
//
#include <hip/hip_runtime.h>
#include <hip/hip_fp16.h>
#include <math.h>

#define TSTEPS 6
#define NN 20000
#define NE 320000
#define INF 11
#define XPAD 16   // padded feature stride for x-side buffers
#define HID 64
#define OUTF 3
#define NPW 4     // nodes per wave in gate/cand kernels (NN % NPW == 0)

__device__ __forceinline__ float bcast(float v, int l) {
    return __uint_as_float(__builtin_amdgcn_readlane(__float_as_uint(v), l));
}

// overflow-safe fast tanh: e2 in (0,1], no inf/NaN for any finite a
__device__ __forceinline__ float tanh_safe(float a) {
    float e2 = __expf(-2.0f * fabsf(a));
    float t = (1.0f - e2) / (1.0f + e2);
    return copysignf(t, a);
}

// ---------------- graph-structure kernels (once per call) ----------------

__global__ void k_deg(const int* __restrict__ src, float* __restrict__ deg, int E) {
    int e = blockIdx.x * blockDim.x + threadIdx.x;
    if (e < E) atomicAdd(&deg[src[e]], 1.0f);
}

__global__ void k_dis(float* deg, int n) {
    int i = blockIdx.x * blockDim.x + threadIdx.x;
    if (i < n) {
        float d = deg[i];
        deg[i] = d > 0.0f ? rsqrtf(fmaxf(d, 1.0f)) : 0.0f;
    }
}

__global__ void k_ew(const int* __restrict__ src, const int* __restrict__ dst,
                     const float* __restrict__ dis, float* __restrict__ ew, int E) {
    int e = blockIdx.x * blockDim.x + threadIdx.x;
    if (e < E) ew[e] = -dis[src[e]] * dis[dst[e]];
}

__global__ void k_indeg(const int* __restrict__ dst, int* __restrict__ indeg, int E) {
    int e = blockIdx.x * blockDim.x + threadIdx.x;
    if (e < E) atomicAdd(&indeg[dst[e]], 1);
}

// exclusive scan of indeg[0..n) -> rowstart[0..n], single block of 1024
__global__ __launch_bounds__(1024) void k_scan(const int* __restrict__ in,
                                               int* __restrict__ out, int n) {
    __shared__ int buf[1024];
    __shared__ int carry;
    if (threadIdx.x == 0) carry = 0;
    __syncthreads();
    for (int base = 0; base < n; base += 1024) {
        int i = base + (int)threadIdx.x;
        int v = (i < n) ? in[i] : 0;
        buf[threadIdx.x] = v;
        __syncthreads();
        for (int off = 1; off < 1024; off <<= 1) {
            int t = (threadIdx.x >= (unsigned)off) ? buf[threadIdx.x - off] : 0;
            __syncthreads();
            buf[threadIdx.x] += t;
            __syncthreads();
        }
        if (i < n) out[i] = carry + buf[threadIdx.x] - v;  // exclusive
        __syncthreads();
        if (threadIdx.x == 0) carry += buf[1023];
        __syncthreads();
    }
    if (threadIdx.x == 0) out[n] = carry;
}

// fill CSR: permuted src + ew, bucketed by dst
__global__ void k_fill(const int* __restrict__ src, const int* __restrict__ dst,
                       const float* __restrict__ ew, int* __restrict__ cursor,
                       int* __restrict__ perm_src, float* __restrict__ perm_ew, int E) {
    int e = blockIdx.x * blockDim.x + threadIdx.x;
    if (e >= E) return;
    int pos = atomicAdd(&cursor[dst[e]], 1);
    perm_src[pos] = src[e];
    perm_ew[pos] = ew[e];
}

// ---------------- weight packing (once per call) ----------------
__global__ void k_packh4(const float* __restrict__ Wh, float4* __restrict__ out) {
    int idx = blockIdx.x * blockDim.x + threadIdx.x;
    if (idx >= HID * HID) return;
    int j = idx >> 6, f = idx & 63;
    float4 v;
    v.x = Wh[((0 * 2 + 0) * HID + j) * HID + f];
    v.y = Wh[((0 * 2 + 1) * HID + j) * HID + f];
    v.z = Wh[((1 * 2 + 0) * HID + j) * HID + f];
    v.w = Wh[((1 * 2 + 1) * HID + j) * HID + f];
    out[idx] = v;
}
__global__ void k_packh2(const float* __restrict__ Wh, float2* __restrict__ out) {
    int idx = blockIdx.x * blockDim.x + threadIdx.x;
    if (idx >= HID * HID) return;
    int j = idx >> 6, f = idx & 63;
    float2 v;
    v.x = Wh[((2 * 2 + 0) * HID + j) * HID + f];
    v.y = Wh[((2 * 2 + 1) * HID + j) * HID + f];
    out[idx] = v;
}
__global__ void k_packx4(const float* __restrict__ Wx, float4* __restrict__ out) {
    int idx = blockIdx.x * blockDim.x + threadIdx.x;
    if (idx >= INF * HID) return;
    int i = idx >> 6, f = idx & 63;
    float4 v;
    v.x = Wx[((0 * 2 + 0) * INF + i) * HID + f];
    v.y = Wx[((0 * 2 + 1) * INF + i) * HID + f];
    v.z = Wx[((1 * 2 + 0) * INF + i) * HID + f];
    v.w = Wx[((1 * 2 + 1) * INF + i) * HID + f];
    out[idx] = v;
}
__global__ void k_packx2(const float* __restrict__ Wx, float2* __restrict__ out) {
    int idx = blockIdx.x * blockDim.x + threadIdx.x;
    if (idx >= INF * HID) return;
    int i = idx >> 6, f = idx & 63;
    float2 v;
    v.x = Wx[((2 * 2 + 0) * INF + i) * HID + f];
    v.y = Wx[((2 * 2 + 1) * INF + i) * HID + f];
    out[idx] = v;
}

// ---------------- per-timestep kernels ----------------

// t == 0: x_in = X_seq[0], padded to stride 16; also write f16 shadow for gather
__global__ void k_xin0(const float* __restrict__ Xt, float* __restrict__ xin,
                       __half* __restrict__ xin16, int n) {
    int i = blockIdx.x * blockDim.x + threadIdx.x;
    if (i >= n) return;
    const float* xt = Xt + (size_t)i * INF;
    float* xo = xin + (size_t)i * XPAD;
    __half* xh = xin16 + (size_t)i * XPAD;
#pragma unroll
    for (int k = 0; k < INF; ++k) { float v = xt[k]; xo[k] = v; xh[k] = __float2half(v); }
#pragma unroll
    for (int k = INF; k < XPAD; ++k) { xo[k] = 0.0f; xh[k] = __float2half(0.0f); }
}

// t > 0: cols 3:6 <- u_prev, cols 8:11 <- (u_prev - X_prev[:,3:6]) / dt
__global__ void k_xin(const float* __restrict__ Xt, const float* __restrict__ Xp,
                      const float* __restrict__ uprev, float* __restrict__ xin,
                      __half* __restrict__ xin16, int n) {
    int i = blockIdx.x * blockDim.x + threadIdx.x;
    if (i >= n) return;
    const float* xt = Xt + (size_t)i * INF;
    const float* xp = Xp + (size_t)i * INF;
    const float* up = uprev + (size_t)i * OUTF;
    float* xo = xin + (size_t)i * XPAD;
    __half* xh = xin16 + (size_t)i * XPAD;
    float dt = xt[6] - xp[6];
    float inv = 1.0f / dt;
    float v[XPAD];
    v[0] = xt[0]; v[1] = xt[1]; v[2] = xt[2];
    v[3] = up[0]; v[4] = up[1]; v[5] = up[2];
    v[6] = xt[6]; v[7] = xt[7];
    v[8] = (up[0] - xp[3]) * inv;
    v[9] = (up[1] - xp[4]) * inv;
    v[10] = (up[2] - xp[5]) * inv;
    v[11] = 0.0f; v[12] = 0.0f; v[13] = 0.0f; v[14] = 0.0f; v[15] = 0.0f;
#pragma unroll
    for (int k = 0; k < XPAD; ++k) { xo[k] = v[k]; xh[k] = __float2half(v[k]); }
}

// gather-SpMM, 16-wide padded f16 features: one wave per node, 4 edges/iter
__global__ __launch_bounds__(256) void k_spmm16(
    const int* __restrict__ rowstart, const int* __restrict__ perm_src,
    const float* __restrict__ perm_ew, const __half* __restrict__ x,
    float* __restrict__ out, int n) {
    int node = (int)((blockIdx.x * blockDim.x + threadIdx.x) >> 6);
    int lane = threadIdx.x & 63;
    int f = lane & 15;
    int eo = lane >> 4;  // 0..3
    if (node >= n) return;
    int s = rowstart[node], e = rowstart[node + 1];
    float a0 = 0.0f, a1 = 0.0f;
    int p = s + eo;
    for (; p + 4 < e; p += 8) {
        a0 = fmaf(perm_ew[p], __half2float(x[(size_t)perm_src[p] * XPAD + f]), a0);
        a1 = fmaf(perm_ew[p + 4], __half2float(x[(size_t)perm_src[p + 4] * XPAD + f]), a1);
    }
    for (; p < e; p += 4)
        a0 = fmaf(perm_ew[p], __half2float(x[(size_t)perm_src[p] * XPAD + f]), a0);
    float acc = a0 + a1;
    acc += __shfl_down(acc, 32);
    acc += __shfl_down(acc, 16);
    if (lane < 16) out[(size_t)node * XPAD + f] = acc;
}

// gather-SpMM, 64-wide f16 rows: one wave per node, lane = feature, 4 gathers in flight
__global__ __launch_bounds__(256) void k_spmm64(
    const int* __restrict__ rowstart, const int* __restrict__ perm_src,
    const float* __restrict__ perm_ew, const __half* __restrict__ x,
    float* __restrict__ out, int n) {
    int node = (int)((blockIdx.x * blockDim.x + threadIdx.x) >> 6);
    int f = threadIdx.x & 63;
    if (node >= n) return;
    int s = rowstart[node], e = rowstart[node + 1];
    float a0 = 0.0f, a1 = 0.0f, a2 = 0.0f, a3 = 0.0f;
    int p = s;
    for (; p + 3 < e; p += 4) {
        int s0 = perm_src[p], s1 = perm_src[p + 1];
        int s2 = perm_src[p + 2], s3 = perm_src[p + 3];
        float w0 = perm_ew[p], w1 = perm_ew[p + 1];
        float w2 = perm_ew[p + 2], w3 = perm_ew[p + 3];
        a0 = fmaf(w0, __half2float(x[(size_t)s0 * HID + f]), a0);
        a1 = fmaf(w1, __half2float(x[(size_t)s1 * HID + f]), a1);
        a2 = fmaf(w2, __half2float(x[(size_t)s2 * HID + f]), a2);
        a3 = fmaf(w3, __half2float(x[(size_t)s3 * HID + f]), a3);
    }
    for (; p < e; ++p)
        a0 = fmaf(perm_ew[p], __half2float(x[(size_t)perm_src[p] * HID + f]), a0);
    out[(size_t)node * HID + f] = (a0 + a1) + (a2 + a3);
}

// Z/R gate kernel: NPW nodes per wave, lane f = output channel, packed float4 weights.
// Writes hr (f32) + hr16 (f16 shadow for the next gather).
__global__ __launch_bounds__(256) void k_gates(
    const float* __restrict__ xin, const float* __restrict__ t1x,
    const float* __restrict__ h, const float* __restrict__ t1h,
    const float4* __restrict__ Wx4, const float* __restrict__ bx,
    const float4* __restrict__ Wh4, const float* __restrict__ bh,
    float* __restrict__ Zb, float* __restrict__ hr,
    __half* __restrict__ hr16, int n) {
    int wbase = (int)((blockIdx.x * blockDim.x + threadIdx.x) >> 6) * NPW;
    int lane = threadIdx.x & 63;
    int f = lane;
    if (wbase >= n) return;
    float xrow = xin[(size_t)wbase * XPAD + lane];
    float trow = t1x[(size_t)wbase * XPAD + lane];
    float b0z = bx[0 * HID + f] + bh[0 * HID + f];
    float b0r = bx[1 * HID + f] + bh[1 * HID + f];
    float az[NPW], ar[NPW], hv[NPW], th[NPW];
#pragma unroll
    for (int nn = 0; nn < NPW; ++nn) { az[nn] = b0z; ar[nn] = b0r; }
#pragma unroll
    for (int nn = 0; nn < NPW; ++nn) {
        hv[nn] = h[(size_t)(wbase + nn) * HID + f];
        th[nn] = t1h[(size_t)(wbase + nn) * HID + f];
    }
#pragma unroll
    for (int i = 0; i < INF; ++i) {
        float4 w = Wx4[i * HID + f];
#pragma unroll
        for (int nn = 0; nn < NPW; ++nn) {
            float xv = bcast(xrow, nn * XPAD + i);
            float tv = bcast(trow, nn * XPAD + i);
            az[nn] = fmaf(xv, w.x, fmaf(tv, w.y, az[nn]));
            ar[nn] = fmaf(xv, w.z, fmaf(tv, w.w, ar[nn]));
        }
    }
#pragma unroll 8
    for (int j = 0; j < HID; ++j) {
        float4 w = Wh4[j * HID + f];
#pragma unroll
        for (int nn = 0; nn < NPW; ++nn) {
            float hj = bcast(hv[nn], j);
            float tj = bcast(th[nn], j);
            az[nn] = fmaf(hj, w.x, fmaf(tj, w.y, az[nn]));
            ar[nn] = fmaf(hj, w.z, fmaf(tj, w.w, ar[nn]));
        }
    }
#pragma unroll
    for (int nn = 0; nn < NPW; ++nn) {
        int node = wbase + nn;
        float Z = 1.0f / (1.0f + __expf(-az[nn]));
        float R = 1.0f / (1.0f + __expf(-ar[nn]));
        float hrv = hv[nn] * R;
        Zb[(size_t)node * HID + f] = Z;
        hr[(size_t)node * HID + f] = hrv;
        hr16[(size_t)node * HID + f] = __float2half(hrv);
    }
}

// Candidate + blend + head: packed float2 weights, NPW nodes per wave.
// Writes h (f32, in place) + h16 (f16 shadow for the next step's gather).
__global__ __launch_bounds__(256) void k_cand(
    const float* __restrict__ xin, const float* __restrict__ t1x,
    float* __restrict__ h, const float* __restrict__ hr,
    const float* __restrict__ t1hr,
    const float2* __restrict__ Wx2, const float* __restrict__ bx,
    const float2* __restrict__ Wh2, const float* __restrict__ bh,
    const float* __restrict__ Zb,
    const float* __restrict__ hw, const float* __restrict__ hb,
    __half* __restrict__ h16, float* __restrict__ out, int n) {
    int wbase = (int)((blockIdx.x * blockDim.x + threadIdx.x) >> 6) * NPW;
    int lane = threadIdx.x & 63;
    int f = lane;
    if (wbase >= n) return;
    float xrow = xin[(size_t)wbase * XPAD + lane];
    float trow = t1x[(size_t)wbase * XPAD + lane];
    float b0 = bx[2 * HID + f] + bh[2 * HID + f];
    float ah[NPW], hrv[NPW], thr[NPW];
#pragma unroll
    for (int nn = 0; nn < NPW; ++nn) ah[nn] = b0;
#pragma unroll
    for (int nn = 0; nn < NPW; ++nn) {
        hrv[nn] = hr[(size_t)(wbase + nn) * HID + f];
        thr[nn] = t1hr[(size_t)(wbase + nn) * HID + f];
    }
#pragma unroll
    for (int i = 0; i < INF; ++i) {
        float2 w = Wx2[i * HID + f];
#pragma unroll
        for (int nn = 0; nn < NPW; ++nn) {
            float xv = bcast(xrow, nn * XPAD + i);
            float tv = bcast(trow, nn * XPAD + i);
            ah[nn] = fmaf(xv, w.x, fmaf(tv, w.y, ah[nn]));
        }
    }
#pragma unroll 8
    for (int j = 0; j < HID; ++j) {
        float2 w = Wh2[j * HID + f];
#pragma unroll
        for (int nn = 0; nn < NPW; ++nn) {
            float hj = bcast(hrv[nn], j);
            float tj = bcast(thr[nn], j);
            ah[nn] = fmaf(hj, w.x, fmaf(tj, w.y, ah[nn]));
        }
    }
#pragma unroll
    for (int nn = 0; nn < NPW; ++nn) {
        int node = wbase + nn;
        float Ht = tanh_safe(ah[nn]);
        float z = Zb[(size_t)node * HID + f];
        float hv = h[(size_t)node * HID + f];
        float hnew = z * hv + (1.0f - z) * Ht;
        h[(size_t)node * HID + f] = hnew;
        h16[(size_t)node * HID + f] = __float2half(hnew);
#pragma unroll
        for (int o = 0; o < OUTF; ++o) {
            float v = hnew * hw[f * OUTF + o];
            for (int off = 32; off; off >>= 1) v += __shfl_down(v, off);
            if (f == 0) out[(size_t)node * OUTF + o] = v + hb[o];
        }
    }
}

extern "C" void kernel_launch(void* const* d_in, const int* in_sizes, int n_in,
                              void* d_out, int out_size, void* d_ws, size_t ws_size,
                              hipStream_t stream) {
    const float* X_seq = (const float*)d_in[0];    // [6, 20000, 11]
    const int* edge = (const int*)d_in[1];         // [2, 320000]
    const float* Wx = (const float*)d_in[2];       // [3, 2, 11, 64]
    const float* bx = (const float*)d_in[3];       // [3, 64]
    const float* Wh = (const float*)d_in[4];       // [3, 2, 64, 64]
    const float* bh = (const float*)d_in[5];       // [3, 64]
    const float* head_W = (const float*)d_in[6];   // [64, 3]
    const float* head_b = (const float*)d_in[7];   // [3]
    float* out = (float*)d_out;                    // [6, 20000, 3]

    const int* src = edge;
    const int* dst = edge + NE;

    // workspace layout (floats). Packed weights first for 16B alignment.
    float* ws = (float*)d_ws;
    float4* Wh4g   = (float4*)ws;                       // 4096 float4 = 16384 f
    float4* Wx4g   = (float4*)(ws + 16384);             // 704 float4  = 2816 f
    float2* Wh2c   = (float2*)(ws + 16384 + 2816);      // 4096 float2 = 8192 f
    float2* Wx2c   = (float2*)(ws + 16384 + 2816 + 8192); // 704 float2 = 1408 f
    float* fbase   = ws + 28800;
    float* dis      = fbase;                      // N
    float* ew       = dis + NN;                   // E
    float* perm_ew  = ew + NE;                    // E
    float* xin      = perm_ew + NE;               // N*16
    float* t1x      = xin + NN * XPAD;            // N*16
    float* h        = t1x + NN * XPAD;            // N*64
    float* t1h      = h + NN * HID;               // N*64 (reused for t1hr)
    float* Zb       = t1h + NN * HID;             // N*64
    float* hr       = Zb + NN * HID;              // N*64
    int* indeg      = (int*)(hr + NN * HID);      // N
    int* rowstart   = indeg + NN;                 // N+1
    int* cursor     = rowstart + NN + 1;          // N
    int* perm_src   = cursor + NN;                // E
    // f16 shadow buffers (2-byte elems), after int region
    __half* h16    = (__half*)(perm_src + NE);            // N*64 halves
    __half* hr16   = h16 + (size_t)NN * HID;              // N*64
    __half* xin16  = hr16 + (size_t)NN * HID;             // N*16

    // --- graph structure + weight packing (once per call) ---
    hipMemsetAsync(dis, 0, NN * sizeof(float), stream);
    hipMemsetAsync(indeg, 0, NN * sizeof(int), stream);
    k_deg<<<(NE + 255) / 256, 256, 0, stream>>>(src, dis, NE);
    k_dis<<<(NN + 255) / 256, 256, 0, stream>>>(dis, NN);
    k_ew<<<(NE + 255) / 256, 256, 0, stream>>>(src, dst, dis, ew, NE);
    k_indeg<<<(NE + 255) / 256, 256, 0, stream>>>(dst, indeg, NE);
    k_scan<<<1, 1024, 0, stream>>>(indeg, rowstart, NN);
    hipMemcpyAsync(cursor, rowstart, NN * sizeof(int), hipMemcpyDeviceToDevice, stream);
    k_fill<<<(NE + 255) / 256, 256, 0, stream>>>(src, dst, ew, cursor, perm_src, perm_ew, NE);
    k_packh4<<<(HID * HID + 255) / 256, 256, 0, stream>>>(Wh, Wh4g);
    k_packh2<<<(HID * HID + 255) / 256, 256, 0, stream>>>(Wh, Wh2c);
    k_packx4<<<(INF * HID + 255) / 256, 256, 0, stream>>>(Wx, Wx4g);
    k_packx2<<<(INF * HID + 255) / 256, 256, 0, stream>>>(Wx, Wx2c);

    // h0 = 0 (f32 and f16 shadow; 0x0000 == +0.0h)
    hipMemsetAsync(h, 0, NN * HID * sizeof(float), stream);
    hipMemsetAsync(h16, 0, NN * HID * sizeof(__half), stream);

    const int waves_grid = (NN * 64 + 255) / 256;                    // 1 node/wave
    const int gates_grid = ((NN + NPW - 1) / NPW * 64 + 255) / 256;  // NPW nodes/wave

    for (int t = 0; t < TSTEPS; ++t) {
        const float* Xt = X_seq + (size_t)t * NN * INF;

        if (t == 0) {
            k_xin0<<<(NN + 255) / 256, 256, 0, stream>>>(Xt, xin, xin16, NN);
        } else {
            const float* Xp = X_seq + (size_t)(t - 1) * NN * INF;
            const float* uprev = out + (size_t)(t - 1) * NN * OUTF;
            k_xin<<<(NN + 255) / 256, 256, 0, stream>>>(Xt, Xp, uprev, xin, xin16, NN);
        }

        k_spmm16<<<waves_grid, 256, 0, stream>>>(rowstart, perm_src, perm_ew, xin16, t1x, NN);
        k_spmm64<<<waves_grid, 256, 0, stream>>>(rowstart, perm_src, perm_ew, h16, t1h, NN);

        k_gates<<<gates_grid, 256, 0, stream>>>(xin, t1x, h, t1h, Wx4g, bx, Wh4g, bh,
                                                Zb, hr, hr16, NN);

        k_spmm64<<<waves_grid, 256, 0, stream>>>(rowstart, perm_src, perm_ew, hr16, t1h, NN);

        k_cand<<<gates_grid, 256, 0, stream>>>(xin, t1x, h, hr, t1h, Wx2c, bx, Wh2c, bh,
                                               Zb, head_W, head_b, h16,
                                               out + (size_t)t * NN * OUTF, NN);
    }
}

// Round 8
// 531.313 us; speedup vs baseline: 1.5228x; 1.2545x over previous
//
#include <hip/hip_runtime.h>
#include <hip/hip_fp16.h>
#include <math.h>

#define TSTEPS 6
#define NN 20000
#define NE 320000
#define INF 11
#define XPAD 16   // padded feature stride for x-side buffers
#define HID 64
#define OUTF 3
#define NPW 4     // nodes per wave in fused kernels (NN % (4*NPW*4waves)==0)

__device__ __forceinline__ float bcast(float v, int l) {
    return __uint_as_float(__builtin_amdgcn_readlane(__float_as_uint(v), l));
}

// overflow-safe fast tanh: e2 in (0,1], no inf/NaN for any finite a
__device__ __forceinline__ float tanh_safe(float a) {
    float e2 = __expf(-2.0f * fabsf(a));
    float t = (1.0f - e2) / (1.0f + e2);
    return copysignf(t, a);
}

// ---------------- graph-structure kernels (once per call) ----------------

__global__ void k_deg(const int* __restrict__ src, float* __restrict__ deg, int E) {
    int e = blockIdx.x * blockDim.x + threadIdx.x;
    if (e < E) atomicAdd(&deg[src[e]], 1.0f);
}

__global__ void k_dis(float* deg, int n) {
    int i = blockIdx.x * blockDim.x + threadIdx.x;
    if (i < n) {
        float d = deg[i];
        deg[i] = d > 0.0f ? rsqrtf(fmaxf(d, 1.0f)) : 0.0f;
    }
}

__global__ void k_ew(const int* __restrict__ src, const int* __restrict__ dst,
                     const float* __restrict__ dis, float* __restrict__ ew, int E) {
    int e = blockIdx.x * blockDim.x + threadIdx.x;
    if (e < E) ew[e] = -dis[src[e]] * dis[dst[e]];
}

__global__ void k_indeg(const int* __restrict__ dst, int* __restrict__ indeg, int E) {
    int e = blockIdx.x * blockDim.x + threadIdx.x;
    if (e < E) atomicAdd(&indeg[dst[e]], 1);
}

// exclusive scan of indeg[0..n) -> rowstart[0..n], single block of 1024
__global__ __launch_bounds__(1024) void k_scan(const int* __restrict__ in,
                                               int* __restrict__ out, int n) {
    __shared__ int buf[1024];
    __shared__ int carry;
    if (threadIdx.x == 0) carry = 0;
    __syncthreads();
    for (int base = 0; base < n; base += 1024) {
        int i = base + (int)threadIdx.x;
        int v = (i < n) ? in[i] : 0;
        buf[threadIdx.x] = v;
        __syncthreads();
        for (int off = 1; off < 1024; off <<= 1) {
            int t = (threadIdx.x >= (unsigned)off) ? buf[threadIdx.x - off] : 0;
            __syncthreads();
            buf[threadIdx.x] += t;
            __syncthreads();
        }
        if (i < n) out[i] = carry + buf[threadIdx.x] - v;  // exclusive
        __syncthreads();
        if (threadIdx.x == 0) carry += buf[1023];
        __syncthreads();
    }
    if (threadIdx.x == 0) out[n] = carry;
}

// fill CSR: packed {src, ew} int2, bucketed by dst
__global__ void k_fill(const int* __restrict__ src, const int* __restrict__ dst,
                       const float* __restrict__ ew, int* __restrict__ cursor,
                       int2* __restrict__ pack, int E) {
    int e = blockIdx.x * blockDim.x + threadIdx.x;
    if (e >= E) return;
    int pos = atomicAdd(&cursor[dst[e]], 1);
    int2 v;
    v.x = src[e];
    v.y = __float_as_int(ew[e]);
    pack[pos] = v;
}

// ---------------- weight packing (once per call) ----------------
__global__ void k_packh4(const float* __restrict__ Wh, float4* __restrict__ out) {
    int idx = blockIdx.x * blockDim.x + threadIdx.x;
    if (idx >= HID * HID) return;
    int j = idx >> 6, f = idx & 63;
    float4 v;
    v.x = Wh[((0 * 2 + 0) * HID + j) * HID + f];
    v.y = Wh[((0 * 2 + 1) * HID + j) * HID + f];
    v.z = Wh[((1 * 2 + 0) * HID + j) * HID + f];
    v.w = Wh[((1 * 2 + 1) * HID + j) * HID + f];
    out[idx] = v;
}
__global__ void k_packh2(const float* __restrict__ Wh, float2* __restrict__ out) {
    int idx = blockIdx.x * blockDim.x + threadIdx.x;
    if (idx >= HID * HID) return;
    int j = idx >> 6, f = idx & 63;
    float2 v;
    v.x = Wh[((2 * 2 + 0) * HID + j) * HID + f];
    v.y = Wh[((2 * 2 + 1) * HID + j) * HID + f];
    out[idx] = v;
}
__global__ void k_packx4(const float* __restrict__ Wx, float4* __restrict__ out) {
    int idx = blockIdx.x * blockDim.x + threadIdx.x;
    if (idx >= INF * HID) return;
    int i = idx >> 6, f = idx & 63;
    float4 v;
    v.x = Wx[((0 * 2 + 0) * INF + i) * HID + f];
    v.y = Wx[((0 * 2 + 1) * INF + i) * HID + f];
    v.z = Wx[((1 * 2 + 0) * INF + i) * HID + f];
    v.w = Wx[((1 * 2 + 1) * INF + i) * HID + f];
    out[idx] = v;
}
__global__ void k_packx2(const float* __restrict__ Wx, float2* __restrict__ out) {
    int idx = blockIdx.x * blockDim.x + threadIdx.x;
    if (idx >= INF * HID) return;
    int i = idx >> 6, f = idx & 63;
    float2 v;
    v.x = Wx[((2 * 2 + 0) * INF + i) * HID + f];
    v.y = Wx[((2 * 2 + 1) * INF + i) * HID + f];
    out[idx] = v;
}

// ---------------- per-timestep kernels ----------------

// t == 0: x_in = X_seq[0], padded to stride 16; also f16 shadow for gather
__global__ void k_xin0(const float* __restrict__ Xt, float* __restrict__ xin,
                       __half* __restrict__ xin16, int n) {
    int i = blockIdx.x * blockDim.x + threadIdx.x;
    if (i >= n) return;
    const float* xt = Xt + (size_t)i * INF;
    float* xo = xin + (size_t)i * XPAD;
    __half* xh = xin16 + (size_t)i * XPAD;
#pragma unroll
    for (int k = 0; k < INF; ++k) { float v = xt[k]; xo[k] = v; xh[k] = __float2half(v); }
#pragma unroll
    for (int k = INF; k < XPAD; ++k) { xo[k] = 0.0f; xh[k] = __float2half(0.0f); }
}

// t > 0: cols 3:6 <- u_prev, cols 8:11 <- (u_prev - X_prev[:,3:6]) / dt
__global__ void k_xin(const float* __restrict__ Xt, const float* __restrict__ Xp,
                      const float* __restrict__ uprev, float* __restrict__ xin,
                      __half* __restrict__ xin16, int n) {
    int i = blockIdx.x * blockDim.x + threadIdx.x;
    if (i >= n) return;
    const float* xt = Xt + (size_t)i * INF;
    const float* xp = Xp + (size_t)i * INF;
    const float* up = uprev + (size_t)i * OUTF;
    float* xo = xin + (size_t)i * XPAD;
    __half* xh = xin16 + (size_t)i * XPAD;
    float dt = xt[6] - xp[6];
    float inv = 1.0f / dt;
    float v[XPAD];
    v[0] = xt[0]; v[1] = xt[1]; v[2] = xt[2];
    v[3] = up[0]; v[4] = up[1]; v[5] = up[2];
    v[6] = xt[6]; v[7] = xt[7];
    v[8] = (up[0] - xp[3]) * inv;
    v[9] = (up[1] - xp[4]) * inv;
    v[10] = (up[2] - xp[5]) * inv;
    v[11] = 0.0f; v[12] = 0.0f; v[13] = 0.0f; v[14] = 0.0f; v[15] = 0.0f;
#pragma unroll
    for (int k = 0; k < XPAD; ++k) { xo[k] = v[k]; xh[k] = __float2half(v[k]); }
}

// Fused: {x-gather + h-gather (shared edge stream)} + Z/R dense. No LDS.
// 256 threads = 4 waves x NPW nodes = 16 nodes/block.
__global__ __launch_bounds__(256) void k_gz(
    const int* __restrict__ rowstart, const int2* __restrict__ pack,
    const float* __restrict__ xin, const __half* __restrict__ xin16,
    const __half* __restrict__ h16,
    const float4* __restrict__ Wx4, const float* __restrict__ bx,
    const float4* __restrict__ Wh4, const float* __restrict__ bh,
    float* __restrict__ t1x, __half* __restrict__ Zb16,
    __half* __restrict__ hr16, int n) {
    int wid = __builtin_amdgcn_readfirstlane(
        (int)((blockIdx.x * blockDim.x + threadIdx.x) >> 6));
    int wbase = wid * NPW;
    int lane = threadIdx.x & 63;
    int f16i = lane & 15;
    if (wbase >= n) return;

    float thg[NPW], axv[NPW], hv[NPW];
#pragma unroll
    for (int nn = 0; nn < NPW; ++nn) {
        int node = wbase + nn;
        int s = rowstart[node], e = rowstart[node + 1];
        float a0 = 0, a1 = 0, a2 = 0, a3 = 0;   // h accumulators
        float c0 = 0, c1 = 0, c2 = 0, c3 = 0;   // x accumulators
        int p = s;
        for (; p + 3 < e; p += 4) {
            int2 e0 = pack[p], e1 = pack[p + 1], e2 = pack[p + 2], e3 = pack[p + 3];
            float w0 = __int_as_float(e0.y), w1 = __int_as_float(e1.y);
            float w2 = __int_as_float(e2.y), w3 = __int_as_float(e3.y);
            a0 = fmaf(w0, __half2float(h16[(size_t)e0.x * HID + lane]), a0);
            a1 = fmaf(w1, __half2float(h16[(size_t)e1.x * HID + lane]), a1);
            a2 = fmaf(w2, __half2float(h16[(size_t)e2.x * HID + lane]), a2);
            a3 = fmaf(w3, __half2float(h16[(size_t)e3.x * HID + lane]), a3);
            c0 = fmaf(w0, __half2float(xin16[(size_t)e0.x * XPAD + f16i]), c0);
            c1 = fmaf(w1, __half2float(xin16[(size_t)e1.x * XPAD + f16i]), c1);
            c2 = fmaf(w2, __half2float(xin16[(size_t)e2.x * XPAD + f16i]), c2);
            c3 = fmaf(w3, __half2float(xin16[(size_t)e3.x * XPAD + f16i]), c3);
        }
        for (; p < e; ++p) {
            int2 e0 = pack[p];
            float w0 = __int_as_float(e0.y);
            a0 = fmaf(w0, __half2float(h16[(size_t)e0.x * HID + lane]), a0);
            c0 = fmaf(w0, __half2float(xin16[(size_t)e0.x * XPAD + f16i]), c0);
        }
        thg[nn] = (a0 + a1) + (a2 + a3);
        axv[nn] = (c0 + c1) + (c2 + c3);  // same value in all 4 lane-groups
        hv[nn] = __half2float(h16[(size_t)node * HID + lane]);
    }
    // persist t1x (fp32) for k_gc
#pragma unroll
    for (int nn = 0; nn < NPW; ++nn)
        if (lane < 16) t1x[(size_t)(wbase + nn) * XPAD + lane] = axv[nn];

    // dense Z/R
    float xrow = xin[(size_t)wbase * XPAD + lane];  // 4 nodes x 16 feats coalesced
    float b0z = bx[0 * HID + lane] + bh[0 * HID + lane];
    float b0r = bx[1 * HID + lane] + bh[1 * HID + lane];
    float az[NPW], ar[NPW];
#pragma unroll
    for (int nn = 0; nn < NPW; ++nn) { az[nn] = b0z; ar[nn] = b0r; }
#pragma unroll
    for (int i = 0; i < INF; ++i) {
        float4 w = Wx4[i * HID + lane];
#pragma unroll
        for (int nn = 0; nn < NPW; ++nn) {
            float xv = bcast(xrow, nn * XPAD + i);
            float tv = bcast(axv[nn], i);
            az[nn] = fmaf(xv, w.x, fmaf(tv, w.y, az[nn]));
            ar[nn] = fmaf(xv, w.z, fmaf(tv, w.w, ar[nn]));
        }
    }
#pragma unroll 8
    for (int j = 0; j < HID; ++j) {
        float4 w = Wh4[j * HID + lane];
#pragma unroll
        for (int nn = 0; nn < NPW; ++nn) {
            float hj = bcast(hv[nn], j);
            float tj = bcast(thg[nn], j);
            az[nn] = fmaf(hj, w.x, fmaf(tj, w.y, az[nn]));
            ar[nn] = fmaf(hj, w.z, fmaf(tj, w.w, ar[nn]));
        }
    }
#pragma unroll
    for (int nn = 0; nn < NPW; ++nn) {
        int node = wbase + nn;
        float Z = 1.0f / (1.0f + __expf(-az[nn]));
        float R = 1.0f / (1.0f + __expf(-ar[nn]));
        Zb16[(size_t)node * HID + lane] = __float2half(Z);
        hr16[(size_t)node * HID + lane] = __float2half(hv[nn] * R);
    }
}

// Fused: hr-gather + candidate dense + blend + head. No LDS.
__global__ __launch_bounds__(256) void k_gc(
    const int* __restrict__ rowstart, const int2* __restrict__ pack,
    const float* __restrict__ xin, const float* __restrict__ t1x,
    float* __restrict__ h, __half* __restrict__ h16,
    const __half* __restrict__ hr16,
    const float2* __restrict__ Wx2, const float* __restrict__ bx,
    const float2* __restrict__ Wh2, const float* __restrict__ bh,
    const __half* __restrict__ Zb16,
    const float* __restrict__ hw, const float* __restrict__ hb,
    float* __restrict__ out, int n) {
    int wid = __builtin_amdgcn_readfirstlane(
        (int)((blockIdx.x * blockDim.x + threadIdx.x) >> 6));
    int wbase = wid * NPW;
    int lane = threadIdx.x & 63;
    if (wbase >= n) return;

    float thg[NPW], hrv[NPW];
#pragma unroll
    for (int nn = 0; nn < NPW; ++nn) {
        int node = wbase + nn;
        int s = rowstart[node], e = rowstart[node + 1];
        float a0 = 0, a1 = 0, a2 = 0, a3 = 0;
        int p = s;
        for (; p + 3 < e; p += 4) {
            int2 e0 = pack[p], e1 = pack[p + 1], e2 = pack[p + 2], e3 = pack[p + 3];
            a0 = fmaf(__int_as_float(e0.y), __half2float(hr16[(size_t)e0.x * HID + lane]), a0);
            a1 = fmaf(__int_as_float(e1.y), __half2float(hr16[(size_t)e1.x * HID + lane]), a1);
            a2 = fmaf(__int_as_float(e2.y), __half2float(hr16[(size_t)e2.x * HID + lane]), a2);
            a3 = fmaf(__int_as_float(e3.y), __half2float(hr16[(size_t)e3.x * HID + lane]), a3);
        }
        for (; p < e; ++p) {
            int2 e0 = pack[p];
            a0 = fmaf(__int_as_float(e0.y), __half2float(hr16[(size_t)e0.x * HID + lane]), a0);
        }
        thg[nn] = (a0 + a1) + (a2 + a3);
        hrv[nn] = __half2float(hr16[(size_t)node * HID + lane]);
    }

    float xrow = xin[(size_t)wbase * XPAD + lane];
    float trow = t1x[(size_t)wbase * XPAD + lane];
    float b0 = bx[2 * HID + lane] + bh[2 * HID + lane];
    float ah[NPW];
#pragma unroll
    for (int nn = 0; nn < NPW; ++nn) ah[nn] = b0;
#pragma unroll
    for (int i = 0; i < INF; ++i) {
        float2 w = Wx2[i * HID + lane];
#pragma unroll
        for (int nn = 0; nn < NPW; ++nn) {
            float xv = bcast(xrow, nn * XPAD + i);
            float tv = bcast(trow, nn * XPAD + i);
            ah[nn] = fmaf(xv, w.x, fmaf(tv, w.y, ah[nn]));
        }
    }
#pragma unroll 8
    for (int j = 0; j < HID; ++j) {
        float2 w = Wh2[j * HID + lane];
#pragma unroll
        for (int nn = 0; nn < NPW; ++nn) {
            float hj = bcast(hrv[nn], j);
            float tj = bcast(thg[nn], j);
            ah[nn] = fmaf(hj, w.x, fmaf(tj, w.y, ah[nn]));
        }
    }
#pragma unroll
    for (int nn = 0; nn < NPW; ++nn) {
        int node = wbase + nn;
        float Ht = tanh_safe(ah[nn]);
        float z = __half2float(Zb16[(size_t)node * HID + lane]);
        float hv = h[(size_t)node * HID + lane];
        float hnew = z * hv + (1.0f - z) * Ht;
        h[(size_t)node * HID + lane] = hnew;
        h16[(size_t)node * HID + lane] = __float2half(hnew);
#pragma unroll
        for (int o = 0; o < OUTF; ++o) {
            float v = hnew * hw[lane * OUTF + o];
            for (int off = 32; off; off >>= 1) v += __shfl_down(v, off);
            if (lane == 0) out[(size_t)node * OUTF + o] = v + hb[o];
        }
    }
}

extern "C" void kernel_launch(void* const* d_in, const int* in_sizes, int n_in,
                              void* d_out, int out_size, void* d_ws, size_t ws_size,
                              hipStream_t stream) {
    const float* X_seq = (const float*)d_in[0];    // [6, 20000, 11]
    const int* edge = (const int*)d_in[1];         // [2, 320000]
    const float* Wx = (const float*)d_in[2];       // [3, 2, 11, 64]
    const float* bx = (const float*)d_in[3];       // [3, 64]
    const float* Wh = (const float*)d_in[4];       // [3, 2, 64, 64]
    const float* bh = (const float*)d_in[5];       // [3, 64]
    const float* head_W = (const float*)d_in[6];   // [64, 3]
    const float* head_b = (const float*)d_in[7];   // [3]
    float* out = (float*)d_out;                    // [6, 20000, 3]

    const int* src = edge;
    const int* dst = edge + NE;

    // workspace layout. Packed weights first (16B-aligned).
    float* ws = (float*)d_ws;
    float4* Wh4g = (float4*)ws;                         // 4096 float4 = 16384 f
    float4* Wx4g = (float4*)(ws + 16384);               // 704 float4  = 2816 f
    float2* Wh2c = (float2*)(ws + 16384 + 2816);        // 4096 float2 = 8192 f
    float2* Wx2c = (float2*)(ws + 16384 + 2816 + 8192); // 704 float2  = 1408 f
    float* fbase = ws + 28800;
    float* dis   = fbase;                    // N
    float* ew    = dis + NN;                 // E
    float* xin   = ew + NE;                  // N*16
    float* t1x   = xin + NN * XPAD;          // N*16
    float* h     = t1x + NN * XPAD;          // N*64
    int* indeg    = (int*)(h + NN * HID);    // N
    int* rowstart = indeg + NN;              // N+2 (padded for int2 alignment)
    int* cursor   = rowstart + NN + 2;       // N
    int2* pack    = (int2*)(cursor + NN);    // E int2 (8B-aligned by construction)
    __half* h16   = (__half*)(pack + NE);    // N*64
    __half* hr16  = h16 + (size_t)NN * HID;  // N*64
    __half* Zb16  = hr16 + (size_t)NN * HID; // N*64
    __half* xin16 = Zb16 + (size_t)NN * HID; // N*16

    // --- graph structure + weight packing (once per call) ---
    hipMemsetAsync(dis, 0, NN * sizeof(float), stream);
    hipMemsetAsync(indeg, 0, NN * sizeof(int), stream);
    k_deg<<<(NE + 255) / 256, 256, 0, stream>>>(src, dis, NE);
    k_dis<<<(NN + 255) / 256, 256, 0, stream>>>(dis, NN);
    k_ew<<<(NE + 255) / 256, 256, 0, stream>>>(src, dst, dis, ew, NE);
    k_indeg<<<(NE + 255) / 256, 256, 0, stream>>>(dst, indeg, NE);
    k_scan<<<1, 1024, 0, stream>>>(indeg, rowstart, NN);
    hipMemcpyAsync(cursor, rowstart, NN * sizeof(int), hipMemcpyDeviceToDevice, stream);
    k_fill<<<(NE + 255) / 256, 256, 0, stream>>>(src, dst, ew, cursor, pack, NE);
    k_packh4<<<(HID * HID + 255) / 256, 256, 0, stream>>>(Wh, Wh4g);
    k_packh2<<<(HID * HID + 255) / 256, 256, 0, stream>>>(Wh, Wh2c);
    k_packx4<<<(INF * HID + 255) / 256, 256, 0, stream>>>(Wx, Wx4g);
    k_packx2<<<(INF * HID + 255) / 256, 256, 0, stream>>>(Wx, Wx2c);

    // h0 = 0 (f32 and f16 shadow)
    hipMemsetAsync(h, 0, NN * HID * sizeof(float), stream);
    hipMemsetAsync(h16, 0, NN * HID * sizeof(__half), stream);

    // fused kernels: 256 threads = 4 waves x NPW(4) nodes = 16 nodes/block
    const int fused_grid = (NN + 4 * NPW - 1) / (4 * NPW);  // 1250

    for (int t = 0; t < TSTEPS; ++t) {
        const float* Xt = X_seq + (size_t)t * NN * INF;

        if (t == 0) {
            k_xin0<<<(NN + 255) / 256, 256, 0, stream>>>(Xt, xin, xin16, NN);
        } else {
            const float* Xp = X_seq + (size_t)(t - 1) * NN * INF;
            const float* uprev = out + (size_t)(t - 1) * NN * OUTF;
            k_xin<<<(NN + 255) / 256, 256, 0, stream>>>(Xt, Xp, uprev, xin, xin16, NN);
        }

        k_gz<<<fused_grid, 256, 0, stream>>>(rowstart, pack, xin, xin16, h16,
                                             Wx4g, bx, Wh4g, bh,
                                             t1x, Zb16, hr16, NN);

        k_gc<<<fused_grid, 256, 0, stream>>>(rowstart, pack, xin, t1x, h, h16, hr16,
                                             Wx2c, bx, Wh2c, bh, Zb16,
                                             head_W, head_b,
                                             out + (size_t)t * NN * OUTF, NN);
    }
}

// Round 9
// 442.850 us; speedup vs baseline: 1.8270x; 1.1998x over previous
//
#include <hip/hip_runtime.h>
#include <hip/hip_fp16.h>
#include <math.h>

#define TSTEPS 6
#define NN 20000
#define NE 320000
#define INF 11
#define XPAD 16
#define HID 64
#define OUTF 3
#define NPW 4                     // nodes per wave in fused kernels
#define EPMAX (NE + 7 * NN)       // CSR slots after pad-to-8
#define NB ((NN + 255) / 256)     // scan blocks = 79

__device__ __forceinline__ float bcast(float v, int l) {
    return __uint_as_float(__builtin_amdgcn_readlane(__float_as_uint(v), l));
}

__device__ __forceinline__ float tanh_safe(float a) {
    float e2 = __expf(-2.0f * fabsf(a));
    float t = (1.0f - e2) / (1.0f + e2);
    return copysignf(t, a);
}

// ---------------- setup kernels (once per call) ----------------

// count out-degree (for norm) and in-degree (for CSR) in one pass
__global__ void k_cnt(const int* __restrict__ src, const int* __restrict__ dst,
                      int* __restrict__ degi, int* __restrict__ indeg, int E) {
    int e = blockIdx.x * blockDim.x + threadIdx.x;
    if (e >= E) return;
    atomicAdd(&degi[src[e]], 1);
    atomicAdd(&indeg[dst[e]], 1);
}

__global__ void k_dis(const int* __restrict__ degi, float* __restrict__ dis, int n) {
    int i = blockIdx.x * blockDim.x + threadIdx.x;
    if (i < n) {
        float d = (float)degi[i];
        dis[i] = d > 0.0f ? rsqrtf(fmaxf(d, 1.0f)) : 0.0f;
    }
}

// scanA: per-block inclusive scan of padded indeg into part, block totals to bsum
__global__ __launch_bounds__(256) void k_scanA(const int* __restrict__ indeg,
                                               int* __restrict__ part,
                                               int* __restrict__ bsum, int n) {
    int idx = blockIdx.x * 256 + threadIdx.x;
    int lane = threadIdx.x & 63, wv = threadIdx.x >> 6;
    int v = (idx < n) ? ((indeg[idx] + 7) & ~7) : 0;
#pragma unroll
    for (int off = 1; off < 64; off <<= 1) {
        int t = __shfl_up(v, off);
        if (lane >= off) v += t;
    }
    __shared__ int wsum[4];
    if (lane == 63) wsum[wv] = v;
    __syncthreads();
    int add = 0;
    for (int w = 0; w < wv; ++w) add += wsum[w];
    v += add;
    if (idx < n) part[idx] = v;
    if (threadIdx.x == 255) bsum[blockIdx.x] = v;
}

// scanB: exclusive scan of NB block sums (NB <= 128)
__global__ __launch_bounds__(128) void k_scanB(const int* __restrict__ bsum,
                                               int* __restrict__ boff, int nb) {
    int tid = threadIdx.x;
    int lane = tid & 63, wv = tid >> 6;
    int orig = (tid < nb) ? bsum[tid] : 0;
    int v = orig;
#pragma unroll
    for (int off = 1; off < 64; off <<= 1) {
        int t = __shfl_up(v, off);
        if (lane >= off) v += t;
    }
    __shared__ int w0;
    if (lane == 63 && wv == 0) w0 = v;
    __syncthreads();
    if (wv == 1) v += w0;
    if (tid < nb) boff[tid] = v - orig;  // exclusive
}

// scanC: finalize exclusive rowstart (+copy into cursor); rowstart[n] = total
__global__ __launch_bounds__(256) void k_scanC(const int* __restrict__ indeg,
                                               int* __restrict__ part,
                                               const int* __restrict__ boff,
                                               int* __restrict__ cursor, int n) {
    int idx = blockIdx.x * 256 + threadIdx.x;
    if (idx >= n) return;
    int pd = (indeg[idx] + 7) & ~7;
    int incl = part[idx] + boff[blockIdx.x];
    int excl = incl - pd;
    part[idx] = excl;      // part aliases rowstart
    cursor[idx] = excl;
    if (idx == n - 1) part[n] = incl;
}

// fill CSR: packed {src, w} int2 bucketed by dst; w computed inline
__global__ void k_fill(const int* __restrict__ src, const int* __restrict__ dst,
                       const float* __restrict__ dis, int* __restrict__ cursor,
                       int2* __restrict__ pack, int E) {
    int e = blockIdx.x * blockDim.x + threadIdx.x;
    if (e >= E) return;
    int s = src[e], d = dst[e];
    int pos = atomicAdd(&cursor[d], 1);
    int2 v;
    v.x = s;
    v.y = __float_as_int(-dis[s] * dis[d]);
    pack[pos] = v;
}

// all weight packing in one kernel
__global__ void k_pack(const float* __restrict__ Wh, const float* __restrict__ Wx,
                       float4* __restrict__ Wh4, float2* __restrict__ Wh2,
                       float4* __restrict__ Wx4, float2* __restrict__ Wx2) {
    int idx = blockIdx.x * blockDim.x + threadIdx.x;
    if (idx < HID * HID) {
        int j = idx >> 6, f = idx & 63;
        float4 v4;
        v4.x = Wh[((0 * 2 + 0) * HID + j) * HID + f];
        v4.y = Wh[((0 * 2 + 1) * HID + j) * HID + f];
        v4.z = Wh[((1 * 2 + 0) * HID + j) * HID + f];
        v4.w = Wh[((1 * 2 + 1) * HID + j) * HID + f];
        Wh4[idx] = v4;
        float2 v2;
        v2.x = Wh[((2 * 2 + 0) * HID + j) * HID + f];
        v2.y = Wh[((2 * 2 + 1) * HID + j) * HID + f];
        Wh2[idx] = v2;
    } else if (idx < HID * HID + INF * HID) {
        int k = idx - HID * HID;
        int i = k >> 6, f = k & 63;
        float4 v4;
        v4.x = Wx[((0 * 2 + 0) * INF + i) * HID + f];
        v4.y = Wx[((0 * 2 + 1) * INF + i) * HID + f];
        v4.z = Wx[((1 * 2 + 0) * INF + i) * HID + f];
        v4.w = Wx[((1 * 2 + 1) * INF + i) * HID + f];
        Wx4[k] = v4;
        float2 v2;
        v2.x = Wx[((2 * 2 + 0) * INF + i) * HID + f];
        v2.y = Wx[((2 * 2 + 1) * INF + i) * HID + f];
        Wx2[k] = v2;
    }
}

__global__ void k_hzero(float* __restrict__ h, __half* __restrict__ h16, int nel) {
    int i = blockIdx.x * blockDim.x + threadIdx.x;
    if (i < nel) { h[i] = 0.0f; h16[i] = __float2half(0.0f); }
}

// t == 0 input build
__global__ void k_xin0(const float* __restrict__ Xt, float* __restrict__ xin,
                       __half* __restrict__ xin16, int n) {
    int i = blockIdx.x * blockDim.x + threadIdx.x;
    if (i >= n) return;
    const float* xt = Xt + (size_t)i * INF;
    float* xo = xin + (size_t)i * XPAD;
    __half* xh = xin16 + (size_t)i * XPAD;
#pragma unroll
    for (int k = 0; k < INF; ++k) { float v = xt[k]; xo[k] = v; xh[k] = __float2half(v); }
#pragma unroll
    for (int k = INF; k < XPAD; ++k) { xo[k] = 0.0f; xh[k] = __float2half(0.0f); }
}

// ---------------- fused per-timestep kernels ----------------

// gz: {h-gather + x-gather over padded CSR} + Z/R dense. No LDS.
__global__ __launch_bounds__(256) void k_gz(
    const int* __restrict__ rowstart, const int2* __restrict__ pack,
    const float* __restrict__ xin, const __half* __restrict__ xin16,
    const __half* __restrict__ h16,
    const float4* __restrict__ Wx4, const float* __restrict__ bx,
    const float4* __restrict__ Wh4, const float* __restrict__ bh,
    float* __restrict__ t1x, __half* __restrict__ Zb16,
    __half* __restrict__ hr16, int n) {
    int wid = __builtin_amdgcn_readfirstlane(
        (int)((blockIdx.x * blockDim.x + threadIdx.x) >> 6));
    int wbase = wid * NPW;
    int lane = threadIdx.x & 63;
    int f16i = lane & 15, eo = lane >> 4;
    if (wbase >= n) return;

    float thg[NPW], axv[NPW], hv[NPW];
#pragma unroll
    for (int nn = 0; nn < NPW; ++nn) {
        int node = wbase + nn;
        int s = rowstart[node], e = rowstart[node + 1];  // (e-s) % 8 == 0
        float a0 = 0, a1 = 0, a2 = 0, a3 = 0;
        float c0 = 0, c1 = 0;
        for (int p = s; p < e; p += 8) {
            int2 e0 = pack[p],     e1 = pack[p + 1], e2 = pack[p + 2], e3 = pack[p + 3];
            int2 e4 = pack[p + 4], e5 = pack[p + 5], e6 = pack[p + 6], e7 = pack[p + 7];
            float w0 = __int_as_float(e0.y), w1 = __int_as_float(e1.y);
            float w2 = __int_as_float(e2.y), w3 = __int_as_float(e3.y);
            float w4 = __int_as_float(e4.y), w5 = __int_as_float(e5.y);
            float w6 = __int_as_float(e6.y), w7 = __int_as_float(e7.y);
            // h-gather: 8 coalesced 128B rows
            a0 = fmaf(w0, __half2float(h16[(size_t)e0.x * HID + lane]), a0);
            a1 = fmaf(w1, __half2float(h16[(size_t)e1.x * HID + lane]), a1);
            a2 = fmaf(w2, __half2float(h16[(size_t)e2.x * HID + lane]), a2);
            a3 = fmaf(w3, __half2float(h16[(size_t)e3.x * HID + lane]), a3);
            a0 = fmaf(w4, __half2float(h16[(size_t)e4.x * HID + lane]), a0);
            a1 = fmaf(w5, __half2float(h16[(size_t)e5.x * HID + lane]), a1);
            a2 = fmaf(w6, __half2float(h16[(size_t)e6.x * HID + lane]), a2);
            a3 = fmaf(w7, __half2float(h16[(size_t)e7.x * HID + lane]), a3);
            // x-gather: each lane-group eo handles slots 2*eo, 2*eo+1
            int sx0 = (eo == 0) ? e0.x : (eo == 1) ? e2.x : (eo == 2) ? e4.x : e6.x;
            float wx0 = (eo == 0) ? w0 : (eo == 1) ? w2 : (eo == 2) ? w4 : w6;
            int sx1 = (eo == 0) ? e1.x : (eo == 1) ? e3.x : (eo == 2) ? e5.x : e7.x;
            float wx1 = (eo == 0) ? w1 : (eo == 1) ? w3 : (eo == 2) ? w5 : w7;
            c0 = fmaf(wx0, __half2float(xin16[(size_t)sx0 * XPAD + f16i]), c0);
            c1 = fmaf(wx1, __half2float(xin16[(size_t)sx1 * XPAD + f16i]), c1);
        }
        thg[nn] = (a0 + a1) + (a2 + a3);
        float cx = c0 + c1;
        cx += __shfl_down(cx, 32);
        cx += __shfl_down(cx, 16);
        axv[nn] = cx;  // valid lanes 0..15
        hv[nn] = __half2float(h16[(size_t)node * HID + lane]);
    }
#pragma unroll
    for (int nn = 0; nn < NPW; ++nn)
        if (lane < 16) t1x[(size_t)(wbase + nn) * XPAD + lane] = axv[nn];

    // dense Z/R
    float xrow = xin[(size_t)wbase * XPAD + lane];
    float b0z = bx[0 * HID + lane] + bh[0 * HID + lane];
    float b0r = bx[1 * HID + lane] + bh[1 * HID + lane];
    float az[NPW], ar[NPW];
#pragma unroll
    for (int nn = 0; nn < NPW; ++nn) { az[nn] = b0z; ar[nn] = b0r; }
#pragma unroll
    for (int i = 0; i < INF; ++i) {
        float4 w = Wx4[i * HID + lane];
#pragma unroll
        for (int nn = 0; nn < NPW; ++nn) {
            float xv = bcast(xrow, nn * XPAD + i);
            float tv = bcast(axv[nn], i);
            az[nn] = fmaf(xv, w.x, fmaf(tv, w.y, az[nn]));
            ar[nn] = fmaf(xv, w.z, fmaf(tv, w.w, ar[nn]));
        }
    }
#pragma unroll 8
    for (int j = 0; j < HID; ++j) {
        float4 w = Wh4[j * HID + lane];
#pragma unroll
        for (int nn = 0; nn < NPW; ++nn) {
            float hj = bcast(hv[nn], j);
            float tj = bcast(thg[nn], j);
            az[nn] = fmaf(hj, w.x, fmaf(tj, w.y, az[nn]));
            ar[nn] = fmaf(hj, w.z, fmaf(tj, w.w, ar[nn]));
        }
    }
#pragma unroll
    for (int nn = 0; nn < NPW; ++nn) {
        int node = wbase + nn;
        float Z = 1.0f / (1.0f + __expf(-az[nn]));
        float R = 1.0f / (1.0f + __expf(-ar[nn]));
        Zb16[(size_t)node * HID + lane] = __float2half(Z);
        hr16[(size_t)node * HID + lane] = __float2half(hv[nn] * R);
    }
}

// gc: hr-gather + candidate + blend + head + NEXT-STEP xin build. No LDS.
__global__ __launch_bounds__(256) void k_gc(
    const int* __restrict__ rowstart, const int2* __restrict__ pack,
    const float* __restrict__ xin, const float* __restrict__ t1x,
    float* __restrict__ h, __half* __restrict__ h16,
    const __half* __restrict__ hr16,
    const float2* __restrict__ Wx2, const float* __restrict__ bx,
    const float2* __restrict__ Wh2, const float* __restrict__ bh,
    const __half* __restrict__ Zb16,
    const float* __restrict__ hw, const float* __restrict__ hb,
    float* __restrict__ out,
    const float* __restrict__ Xcur, const float* __restrict__ Xnxt,
    float* __restrict__ xin_w, __half* __restrict__ xin16_w,
    int last, int n) {
    int wid = __builtin_amdgcn_readfirstlane(
        (int)((blockIdx.x * blockDim.x + threadIdx.x) >> 6));
    int wbase = wid * NPW;
    int lane = threadIdx.x & 63;
    if (wbase >= n) return;

    float thg[NPW], hrv[NPW];
#pragma unroll
    for (int nn = 0; nn < NPW; ++nn) {
        int node = wbase + nn;
        int s = rowstart[node], e = rowstart[node + 1];
        float a0 = 0, a1 = 0, a2 = 0, a3 = 0;
        for (int p = s; p < e; p += 8) {
            int2 e0 = pack[p],     e1 = pack[p + 1], e2 = pack[p + 2], e3 = pack[p + 3];
            int2 e4 = pack[p + 4], e5 = pack[p + 5], e6 = pack[p + 6], e7 = pack[p + 7];
            a0 = fmaf(__int_as_float(e0.y), __half2float(hr16[(size_t)e0.x * HID + lane]), a0);
            a1 = fmaf(__int_as_float(e1.y), __half2float(hr16[(size_t)e1.x * HID + lane]), a1);
            a2 = fmaf(__int_as_float(e2.y), __half2float(hr16[(size_t)e2.x * HID + lane]), a2);
            a3 = fmaf(__int_as_float(e3.y), __half2float(hr16[(size_t)e3.x * HID + lane]), a3);
            a0 = fmaf(__int_as_float(e4.y), __half2float(hr16[(size_t)e4.x * HID + lane]), a0);
            a1 = fmaf(__int_as_float(e5.y), __half2float(hr16[(size_t)e5.x * HID + lane]), a1);
            a2 = fmaf(__int_as_float(e6.y), __half2float(hr16[(size_t)e6.x * HID + lane]), a2);
            a3 = fmaf(__int_as_float(e7.y), __half2float(hr16[(size_t)e7.x * HID + lane]), a3);
        }
        thg[nn] = (a0 + a1) + (a2 + a3);
        hrv[nn] = __half2float(hr16[(size_t)node * HID + lane]);
    }

    float xrow = xin[(size_t)wbase * XPAD + lane];
    float trow = t1x[(size_t)wbase * XPAD + lane];
    float b0 = bx[2 * HID + lane] + bh[2 * HID + lane];
    float ah[NPW];
#pragma unroll
    for (int nn = 0; nn < NPW; ++nn) ah[nn] = b0;
#pragma unroll
    for (int i = 0; i < INF; ++i) {
        float2 w = Wx2[i * HID + lane];
#pragma unroll
        for (int nn = 0; nn < NPW; ++nn) {
            float xv = bcast(xrow, nn * XPAD + i);
            float tv = bcast(trow, nn * XPAD + i);
            ah[nn] = fmaf(xv, w.x, fmaf(tv, w.y, ah[nn]));
        }
    }
#pragma unroll 8
    for (int j = 0; j < HID; ++j) {
        float2 w = Wh2[j * HID + lane];
#pragma unroll
        for (int nn = 0; nn < NPW; ++nn) {
            float hj = bcast(hrv[nn], j);
            float tj = bcast(thg[nn], j);
            ah[nn] = fmaf(hj, w.x, fmaf(tj, w.y, ah[nn]));
        }
    }
#pragma unroll
    for (int nn = 0; nn < NPW; ++nn) {
        int node = wbase + nn;
        float Ht = tanh_safe(ah[nn]);
        float z = __half2float(Zb16[(size_t)node * HID + lane]);
        float hvv = h[(size_t)node * HID + lane];
        float hnew = z * hvv + (1.0f - z) * Ht;
        h[(size_t)node * HID + lane] = hnew;
        h16[(size_t)node * HID + lane] = __float2half(hnew);
        // head: u = hnew @ hw + hb, broadcast to all lanes
        float u0, u1, u2;
        {
            float v0 = hnew * hw[lane * OUTF + 0];
            float v1 = hnew * hw[lane * OUTF + 1];
            float v2 = hnew * hw[lane * OUTF + 2];
            for (int off = 32; off; off >>= 1) {
                v0 += __shfl_down(v0, off);
                v1 += __shfl_down(v1, off);
                v2 += __shfl_down(v2, off);
            }
            u0 = bcast(v0, 0) + hb[0];
            u1 = bcast(v1, 0) + hb[1];
            u2 = bcast(v2, 0) + hb[2];
        }
        if (lane == 0) {
            float* o = out + (size_t)node * OUTF;
            o[0] = u0; o[1] = u1; o[2] = u2;
        }
        if (!last) {
            // build next step's x_in for this node (node-local)
            const float* x1r = Xnxt + (size_t)node * INF;
            const float* x0r = Xcur + (size_t)node * INF;
            float x1 = (lane < INF) ? x1r[lane] : 0.0f;
            float x0v = (lane >= 3 && lane < 7) ? x0r[lane] : 0.0f;
            float dt = bcast(x1, 6) - bcast(x0v, 6);
            float inv = 1.0f / dt;
            float c3 = bcast(x0v, 3), c4 = bcast(x0v, 4), c5 = bcast(x0v, 5);
            float val;
            if (lane < 3) val = x1;
            else if (lane < 6) val = (lane == 3) ? u0 : (lane == 4) ? u1 : u2;
            else if (lane < 8) val = x1;
            else if (lane < 11) {
                float uu = (lane == 8) ? u0 : (lane == 9) ? u1 : u2;
                float cc = (lane == 8) ? c3 : (lane == 9) ? c4 : c5;
                val = (uu - cc) * inv;
            } else val = 0.0f;
            if (lane < XPAD) {
                xin_w[(size_t)node * XPAD + lane] = val;
                xin16_w[(size_t)node * XPAD + lane] = __float2half(val);
            }
        }
    }
}

extern "C" void kernel_launch(void* const* d_in, const int* in_sizes, int n_in,
                              void* d_out, int out_size, void* d_ws, size_t ws_size,
                              hipStream_t stream) {
    const float* X_seq = (const float*)d_in[0];
    const int* edge = (const int*)d_in[1];
    const float* Wx = (const float*)d_in[2];
    const float* bx = (const float*)d_in[3];
    const float* Wh = (const float*)d_in[4];
    const float* bh = (const float*)d_in[5];
    const float* head_W = (const float*)d_in[6];
    const float* head_b = (const float*)d_in[7];
    float* out = (float*)d_out;

    const int* src = edge;
    const int* dst = edge + NE;

    // ---- workspace layout ----
    float* ws = (float*)d_ws;
    float4* Wh4g = (float4*)ws;                          // 4096 f4
    float4* Wx4g = (float4*)(ws + 16384);                // 704 f4
    float2* Wh2c = (float2*)(ws + 19200);                // 4096 f2
    float2* Wx2c = (float2*)(ws + 27392);                // 704 f2
    float* fbase = ws + 28800;
    float* dis  = fbase;                                 // N
    float* xin  = dis + NN;                              // N*16
    float* t1x  = xin + (size_t)NN * XPAD;               // N*16
    float* h    = t1x + (size_t)NN * XPAD;               // N*64
    int* degi     = (int*)(h + (size_t)NN * HID);        // N
    int* indeg    = degi + NN;                           // N
    int* rowstart = indeg + NN;                          // N+2
    int* cursor   = rowstart + NN + 2;                   // N
    int* bsum     = cursor + NN;                         // 128
    int* boff     = bsum + 128;                          // 128
    int2* pack    = (int2*)(boff + 128);                 // EPMAX int2
    __half* h16   = (__half*)(pack + EPMAX);             // N*64
    __half* hr16  = h16 + (size_t)NN * HID;              // N*64
    __half* Zb16  = hr16 + (size_t)NN * HID;             // N*64
    __half* xin16 = Zb16 + (size_t)NN * HID;             // N*16

    // ---- setup (once per call) ----
    hipMemsetAsync(degi, 0, 2 * NN * sizeof(int), stream);       // degi + indeg
    hipMemsetAsync(pack, 0, (size_t)EPMAX * sizeof(int2), stream); // zero pad slots
    k_cnt<<<(NE + 255) / 256, 256, 0, stream>>>(src, dst, degi, indeg, NE);
    k_dis<<<(NN + 255) / 256, 256, 0, stream>>>(degi, dis, NN);
    k_scanA<<<NB, 256, 0, stream>>>(indeg, rowstart, bsum, NN);
    k_scanB<<<1, 128, 0, stream>>>(bsum, boff, NB);
    k_scanC<<<NB, 256, 0, stream>>>(indeg, rowstart, boff, cursor, NN);
    k_fill<<<(NE + 255) / 256, 256, 0, stream>>>(src, dst, dis, cursor, pack, NE);
    k_pack<<<(HID * HID + INF * HID + 255) / 256, 256, 0, stream>>>(
        Wh, Wx, Wh4g, Wh2c, Wx4g, Wx2c);
    k_hzero<<<(NN * HID + 255) / 256, 256, 0, stream>>>(h, h16, NN * HID);

    // x_in for t = 0
    k_xin0<<<(NN + 255) / 256, 256, 0, stream>>>(X_seq, xin, xin16, NN);

    const int fused_grid = (NN + 4 * NPW - 1) / (4 * NPW);  // 1250

    for (int t = 0; t < TSTEPS; ++t) {
        k_gz<<<fused_grid, 256, 0, stream>>>(rowstart, pack, xin, xin16, h16,
                                             Wx4g, bx, Wh4g, bh,
                                             t1x, Zb16, hr16, NN);

        const float* Xcur = X_seq + (size_t)t * NN * INF;
        const float* Xnxt = (t + 1 < TSTEPS) ? X_seq + (size_t)(t + 1) * NN * INF : X_seq;
        k_gc<<<fused_grid, 256, 0, stream>>>(rowstart, pack, xin, t1x, h, h16, hr16,
                                             Wx2c, bx, Wh2c, bh, Zb16,
                                             head_W, head_b,
                                             out + (size_t)t * NN * OUTF,
                                             Xcur, Xnxt, xin, xin16,
                                             (t + 1 == TSTEPS) ? 1 : 0, NN);
    }
}